// Round 7
// baseline (139.820 us; speedup 1.0000x reference)
//
#include <hip/hip_runtime.h>
#include <hip/hip_bf16.h>

// Problem constants: B=64, N=32, S=256, D=128
#define B_SZ 64

typedef __attribute__((ext_vector_type(8))) short bf16x8;
typedef __attribute__((ext_vector_type(4))) float f32x4;

// RNE fp32->bf16 for FINITE inputs (random-normal data: no NaN/Inf).
// Bit-exact with __float2bfloat16 on finite values; skips the NaN
// cmp/cndmask path the HIP helper carries (~30% fewer VALU ops).
static __device__ __forceinline__ unsigned short f2bf(float f) {
    unsigned int u = __builtin_bit_cast(unsigned int, f);
    u += 0x7FFFu + ((u >> 16) & 1u);    // round-to-nearest-even
    return (unsigned short)(u >> 16);
}

// Load 8 consecutive fp32 (32 B), convert to one bf16x8 fragment.
// MFMA A and B fragments are k-contiguous per lane, so fragments load DIRECTLY
// from the row-major fp32 inputs — no transpose pass needed.
static __device__ __forceinline__ bf16x8 cvt_frag(const float* __restrict__ src) {
    float4 a = reinterpret_cast<const float4*>(src)[0];
    float4 b = reinterpret_cast<const float4*>(src)[1];
    union { bf16x8 v; unsigned short u[8]; } t;
    t.u[0] = f2bf(a.x); t.u[1] = f2bf(a.y); t.u[2] = f2bf(a.z); t.u[3] = f2bf(a.w);
    t.u[4] = f2bf(b.x); t.u[5] = f2bf(b.y); t.u[6] = f2bf(b.z); t.u[7] = f2bf(b.w);
    return t.v;
}

#define MFMA(A, Bv, C) __builtin_amdgcn_mfma_f32_16x16x32_bf16(A, Bv, C, 0, 0, 0)

// Per-batch inner body, compile-time trip count so the bi loop fully unrolls
// and the compiler pipelines bi+1's global loads under bi's cvt/MFMA work.
// In-loop reduction only folds lane-xor 1,2 (DPP-cheap); the remaining
// 4-quad x 4-wave max goes to the padded-LDS tail.
template <int NB>
static __device__ __forceinline__ void run_batches(
        const float* __restrict__ qbase, const bf16x8 (&Bv)[4][4],
        float (&wred)[4][4][4][4][9], int wave, int lane) {
    const int l15 = lane & 15, lhi = lane >> 4;
    #pragma unroll
    for (int bi = 0; bi < NB; ++bi) {
        const float* qb = qbase + (size_t)bi * 4096;
        bf16x8 Af[4][2];                 // [kk][mt]
        #pragma unroll
        for (int kk = 0; kk < 4; ++kk) {
            Af[kk][0] = cvt_frag(qb + kk * 32);            // rows n = l15
            Af[kk][1] = cvt_frag(qb + 2048 + kk * 32);     // rows n = 16 + l15
        }
        f32x4 acc[2][4] = {};            // [mt][nt]
        #pragma unroll
        for (int kk = 0; kk < 4; ++kk)
            #pragma unroll
            for (int nt = 0; nt < 4; ++nt) {
                acc[0][nt] = MFMA(Af[kk][0], Bv[kk][nt], acc[0][nt]);
                acc[1][nt] = MFMA(Af[kk][1], Bv[kk][nt], acc[1][nt]);
            }
        // fold nt, then quad-fold over lane-xor 1,2 (stays within l15 quads)
        #pragma unroll
        for (int mt = 0; mt < 2; ++mt)
            #pragma unroll
            for (int r = 0; r < 4; ++r) {
                float m = fmaxf(fmaxf(acc[mt][0][r], acc[mt][1][r]),
                                fmaxf(acc[mt][2][r], acc[mt][3][r]));
                m = fmaxf(m, __shfl_xor(m, 1, 64));
                m = fmaxf(m, __shfl_xor(m, 2, 64));
                if ((l15 & 3) == 0)
                    wred[bi][wave][lhi][l15 >> 2][mt * 4 + r] = m;
                // value = max over s-residues {quad*4..+3}, row n = mt*16+lhi*4+r
            }
    }
}

// Direct-load B-in-register MaxSim, latency-tolerant version.
// wg < 1024 (pos): x = wg&7 (XCD under default wg%8 placement), i = wg>>3;
//   column c = x*8 + (i&7) -> all 16 blocks of column c land on XCD x, so the
//   128 KiB doc tile is fetched once then L2-served. Block covers 4 batches
//   b in [ (i>>3)*4, +4 ).
// wg >= 1024 (neg): pair b = wg-1024, doc nd[b], single batch, score slot 64.
// Fragment indexing (harness-verified R3/R6 layout):
//   Bv[kk][nt] lane l = doc[s = wave*64 + nt*16 + (l&15)][k = kk*32+(l>>4)*8..+7]
//   Af[kk][mt] lane l = q[b][n = mt*16 + (l&15)]          [k = kk*32+(l>>4)*8..+7]
__global__ __launch_bounds__(256, 4) void maxsim_kernel(const float* __restrict__ q,
                                                        const float* __restrict__ dd,
                                                        const float* __restrict__ nd,
                                                        float* __restrict__ scores) {
    const int wg  = blockIdx.x;
    const int tid = threadIdx.x;
    const int wave = tid >> 6, lane = tid & 63;
    const int l15 = lane & 15, lhi = lane >> 4;

    // [bi][wave][lhi][quad][slot(8)+pad] — pad makes tail/store bank-clean
    __shared__ float wred[4][4][4][4][9];   // 9216 B

    int c, b0, nb;
    const float* docp;
    if (wg < 1024) {
        const int x = wg & 7, i = wg >> 3;
        c   = x * 8 + (i & 7);
        b0  = (i >> 3) * 4;
        nb  = 4;
        docp = dd + (size_t)c * 32768;
    } else {
        b0 = wg - 1024; c = 64; nb = 1;
        docp = nd + (size_t)b0 * 32768;
    }

    // ---- stage this wave's s-chunk (ch = wave) straight into registers ----
    bf16x8 Bv[4][4];                     // [kk][nt]
    {
        const float* base = docp + (size_t)(wave * 64 + l15) * 128 + lhi * 8;
        #pragma unroll
        for (int kk = 0; kk < 4; ++kk)
            #pragma unroll
            for (int nt = 0; nt < 4; ++nt)
                Bv[kk][nt] = cvt_frag(base + nt * 2048 + kk * 32);
    }

    const float* qbase = q + (size_t)b0 * 4096 + (size_t)l15 * 128 + lhi * 8;
    if (nb == 4) run_batches<4>(qbase, Bv, wred, wave, lane);
    else         run_batches<1>(qbase, Bv, wred, wave, lane);
    __syncthreads();

    // ---- tail: max over 4 waves x 4 quads, then sum over the 32 query rows ----
    if (tid < nb * 32) {
        const int bi = tid >> 5, n = tid & 31;
        const int mt = n >> 4, lh = (n >> 2) & 3, r = n & 3;
        const int slot = mt * 4 + r;
        float m = -3.0e38f;
        #pragma unroll
        for (int w = 0; w < 4; ++w)
            #pragma unroll
            for (int qd = 0; qd < 4; ++qd)
                m = fmaxf(m, wred[bi][w][lh][qd][slot]);
        m += __shfl_xor(m, 1, 32);
        m += __shfl_xor(m, 2, 32);
        m += __shfl_xor(m, 4, 32);
        m += __shfl_xor(m, 8, 32);
        m += __shfl_xor(m, 16, 32);
        if (n == 0) scores[(size_t)(b0 + bi) * 65 + c] = m;  // c==64 -> neg slot
    }
}

static __device__ __forceinline__ float softplusf(float x) {
    return fmaxf(x, 0.0f) + log1pf(expf(-fabsf(x)));
}

__global__ __launch_bounds__(64) void loss_kernel(const float* __restrict__ scores,
                                                  float* __restrict__ out) {
    const int b = threadIdx.x;           // 64 threads = 1 wave
    const float* row = scores + b * 65;
    const float pos  = row[b];
    const float negq = row[64];
    float nib = -1e30f;
    #pragma unroll
    for (int c = 0; c < B_SZ; ++c) {
        float v = row[c] - ((c == b) ? 1000000.0f : 0.0f);
        nib = fmaxf(nib, v);
    }
    float t = softplusf(negq - pos) + softplusf(nib - pos);
    t += __shfl_xor(t, 1, 64);
    t += __shfl_xor(t, 2, 64);
    t += __shfl_xor(t, 4, 64);
    t += __shfl_xor(t, 8, 64);
    t += __shfl_xor(t, 16, 64);
    t += __shfl_xor(t, 32, 64);
    if (b == 0) out[0] = t * (0.5f / 64.0f);
}

extern "C" void kernel_launch(void* const* d_in, const int* in_sizes, int n_in,
                              void* d_out, int out_size, void* d_ws, size_t ws_size,
                              hipStream_t stream) {
    const float* q  = (const float*)d_in[0];   // (64, 32, 128)
    const float* dd = (const float*)d_in[1];   // (64, 256, 128)
    const float* nd = (const float*)d_in[2];   // (64, 256, 128)
    float* out = (float*)d_out;

    // Workspace: scores (64 x 65 f32) only.
    float* scores = (float*)d_ws;

    maxsim_kernel<<<1024 + B_SZ, 256, 0, stream>>>(q, dd, nd, scores);
    loss_kernel<<<1, 64, 0, stream>>>(scores, out);
}

// Round 8
// 119.830 us; speedup vs baseline: 1.1668x; 1.1668x over previous
//
#include <hip/hip_runtime.h>
#include <hip/hip_bf16.h>

// Problem constants: B=64, N=32, S=256, D=128
#define B_SZ 64

typedef __attribute__((ext_vector_type(8))) short bf16x8;
typedef __attribute__((ext_vector_type(4))) float f32x4;

// RNE fp32->bf16 for FINITE inputs (random-normal data: no NaN/Inf).
// Bit-exact with __float2bfloat16 on finite values; skips the NaN
// cmp/cndmask path the HIP helper carries (~30% fewer VALU ops).
static __device__ __forceinline__ unsigned short f2bf(float f) {
    unsigned int u = __builtin_bit_cast(unsigned int, f);
    u += 0x7FFFu + ((u >> 16) & 1u);    // round-to-nearest-even
    return (unsigned short)(u >> 16);
}

// Load 8 consecutive fp32 (32 B), convert to one bf16x8 fragment.
// MFMA A and B fragments are k-contiguous per lane, so fragments load DIRECTLY
// from the row-major fp32 inputs — no transpose pass needed.
static __device__ __forceinline__ bf16x8 cvt_frag(const float* __restrict__ src) {
    float4 a = reinterpret_cast<const float4*>(src)[0];
    float4 b = reinterpret_cast<const float4*>(src)[1];
    union { bf16x8 v; unsigned short u[8]; } t;
    t.u[0] = f2bf(a.x); t.u[1] = f2bf(a.y); t.u[2] = f2bf(a.z); t.u[3] = f2bf(a.w);
    t.u[4] = f2bf(b.x); t.u[5] = f2bf(b.y); t.u[6] = f2bf(b.z); t.u[7] = f2bf(b.w);
    return t.v;
}

#define MFMA(A, Bv, C) __builtin_amdgcn_mfma_f32_16x16x32_bf16(A, Bv, C, 0, 0, 0)

// Per-batch inner body, compile-time trip count so the bi loop fully unrolls
// and the compiler pipelines bi+1's global loads under bi's cvt/MFMA work.
// In-loop reduction only folds lane-xor 1,2 (DPP-cheap); the remaining
// 4-quad x 4-wave max goes to the padded-LDS tail.
// NOTE (R7 lesson): this footprint (Bv 64 + Af 16 + acc 32 VGPR/AGPR) needs
// the >=170-reg budget of 3 waves/EU. __launch_bounds__(256,4) made the
// allocator spill Bv/Af to scratch: WRITE_SIZE 31.5 KB -> 49.5 MB, FETCH
// 12.3 -> 66 MB, 1.4x slower despite higher occupancy. Keep min-waves at 3.
template <int NB>
static __device__ __forceinline__ void run_batches(
        const float* __restrict__ qbase, const bf16x8 (&Bv)[4][4],
        float (&wred)[4][4][4][4][9], int wave, int lane) {
    const int l15 = lane & 15, lhi = lane >> 4;
    #pragma unroll
    for (int bi = 0; bi < NB; ++bi) {
        const float* qb = qbase + (size_t)bi * 4096;
        bf16x8 Af[4][2];                 // [kk][mt]
        #pragma unroll
        for (int kk = 0; kk < 4; ++kk) {
            Af[kk][0] = cvt_frag(qb + kk * 32);            // rows n = l15
            Af[kk][1] = cvt_frag(qb + 2048 + kk * 32);     // rows n = 16 + l15
        }
        f32x4 acc[2][4] = {};            // [mt][nt]
        #pragma unroll
        for (int kk = 0; kk < 4; ++kk)
            #pragma unroll
            for (int nt = 0; nt < 4; ++nt) {
                acc[0][nt] = MFMA(Af[kk][0], Bv[kk][nt], acc[0][nt]);
                acc[1][nt] = MFMA(Af[kk][1], Bv[kk][nt], acc[1][nt]);
            }
        // fold nt, then quad-fold over lane-xor 1,2 (stays within l15 quads)
        #pragma unroll
        for (int mt = 0; mt < 2; ++mt)
            #pragma unroll
            for (int r = 0; r < 4; ++r) {
                float m = fmaxf(fmaxf(acc[mt][0][r], acc[mt][1][r]),
                                fmaxf(acc[mt][2][r], acc[mt][3][r]));
                m = fmaxf(m, __shfl_xor(m, 1, 64));
                m = fmaxf(m, __shfl_xor(m, 2, 64));
                if ((l15 & 3) == 0)
                    wred[bi][wave][lhi][l15 >> 2][mt * 4 + r] = m;
                // value = max over s-residues {quad*4..+3}, row n = mt*16+lhi*4+r
            }
    }
}

// Direct-load B-in-register MaxSim, latency-tolerant version.
// wg < 1024 (pos): x = wg&7 (XCD under default wg%8 placement), i = wg>>3;
//   column c = x*8 + (i&7) -> all 16 blocks of column c land on XCD x, so the
//   128 KiB doc tile is fetched once then L2-served. Block covers 4 batches
//   b in [ (i>>3)*4, +4 ).
// wg >= 1024 (neg): pair b = wg-1024, doc nd[b], single batch, score slot 64.
// Fragment indexing (harness-verified R3/R6 layout):
//   Bv[kk][nt] lane l = doc[s = wave*64 + nt*16 + (l&15)][k = kk*32+(l>>4)*8..+7]
//   Af[kk][mt] lane l = q[b][n = mt*16 + (l&15)]          [k = kk*32+(l>>4)*8..+7]
__global__ __launch_bounds__(256, 3) void maxsim_kernel(const float* __restrict__ q,
                                                        const float* __restrict__ dd,
                                                        const float* __restrict__ nd,
                                                        float* __restrict__ scores) {
    const int wg  = blockIdx.x;
    const int tid = threadIdx.x;
    const int wave = tid >> 6, lane = tid & 63;
    const int l15 = lane & 15, lhi = lane >> 4;

    // [bi][wave][lhi][quad][slot(8)+pad] — pad makes tail/store bank-clean
    __shared__ float wred[4][4][4][4][9];   // 9216 B

    int c, b0, nb;
    const float* docp;
    if (wg < 1024) {
        const int x = wg & 7, i = wg >> 3;
        c   = x * 8 + (i & 7);
        b0  = (i >> 3) * 4;
        nb  = 4;
        docp = dd + (size_t)c * 32768;
    } else {
        b0 = wg - 1024; c = 64; nb = 1;
        docp = nd + (size_t)b0 * 32768;
    }

    // ---- stage this wave's s-chunk (ch = wave) straight into registers ----
    bf16x8 Bv[4][4];                     // [kk][nt]
    {
        const float* base = docp + (size_t)(wave * 64 + l15) * 128 + lhi * 8;
        #pragma unroll
        for (int kk = 0; kk < 4; ++kk)
            #pragma unroll
            for (int nt = 0; nt < 4; ++nt)
                Bv[kk][nt] = cvt_frag(base + nt * 2048 + kk * 32);
    }

    const float* qbase = q + (size_t)b0 * 4096 + (size_t)l15 * 128 + lhi * 8;
    if (nb == 4) run_batches<4>(qbase, Bv, wred, wave, lane);
    else         run_batches<1>(qbase, Bv, wred, wave, lane);
    __syncthreads();

    // ---- tail: max over 4 waves x 4 quads, then sum over the 32 query rows ----
    if (tid < nb * 32) {
        const int bi = tid >> 5, n = tid & 31;
        const int mt = n >> 4, lh = (n >> 2) & 3, r = n & 3;
        const int slot = mt * 4 + r;
        float m = -3.0e38f;
        #pragma unroll
        for (int w = 0; w < 4; ++w)
            #pragma unroll
            for (int qd = 0; qd < 4; ++qd)
                m = fmaxf(m, wred[bi][w][lh][qd][slot]);
        m += __shfl_xor(m, 1, 32);
        m += __shfl_xor(m, 2, 32);
        m += __shfl_xor(m, 4, 32);
        m += __shfl_xor(m, 8, 32);
        m += __shfl_xor(m, 16, 32);
        if (n == 0) scores[(size_t)(b0 + bi) * 65 + c] = m;  // c==64 -> neg slot
    }
}

static __device__ __forceinline__ float softplusf(float x) {
    return fmaxf(x, 0.0f) + log1pf(expf(-fabsf(x)));
}

__global__ __launch_bounds__(64) void loss_kernel(const float* __restrict__ scores,
                                                  float* __restrict__ out) {
    const int b = threadIdx.x;           // 64 threads = 1 wave
    const float* row = scores + b * 65;
    const float pos  = row[b];
    const float negq = row[64];
    float nib = -1e30f;
    #pragma unroll
    for (int c = 0; c < B_SZ; ++c) {
        float v = row[c] - ((c == b) ? 1000000.0f : 0.0f);
        nib = fmaxf(nib, v);
    }
    float t = softplusf(negq - pos) + softplusf(nib - pos);
    t += __shfl_xor(t, 1, 64);
    t += __shfl_xor(t, 2, 64);
    t += __shfl_xor(t, 4, 64);
    t += __shfl_xor(t, 8, 64);
    t += __shfl_xor(t, 16, 64);
    t += __shfl_xor(t, 32, 64);
    if (b == 0) out[0] = t * (0.5f / 64.0f);
}

extern "C" void kernel_launch(void* const* d_in, const int* in_sizes, int n_in,
                              void* d_out, int out_size, void* d_ws, size_t ws_size,
                              hipStream_t stream) {
    const float* q  = (const float*)d_in[0];   // (64, 32, 128)
    const float* dd = (const float*)d_in[1];   // (64, 256, 128)
    const float* nd = (const float*)d_in[2];   // (64, 256, 128)
    float* out = (float*)d_out;

    // Workspace: scores (64 x 65 f32) only.
    float* scores = (float*)d_ws;

    maxsim_kernel<<<1024 + B_SZ, 256, 0, stream>>>(q, dd, nd, scores);
    loss_kernel<<<1, 64, 0, stream>>>(scores, out);
}